// Round 1
// baseline (6476.353 us; speedup 1.0000x reference)
//
#include <hip/hip_runtime.h>

#define N_NODES 100000
#define M_EDGES 500000
#define D 128
#define EPB 32          // edges per block (500000 % 32 == 0 -> 15625 blocks)
#define SLOPE 0.01f
#define EPS 1e-5f

// ---------------------------------------------------------------------------
// count_kernel: degree counts (float). Each edge adds 1 to tail (fwd msg dst)
// and 1 to head (back msg dst).
// ---------------------------------------------------------------------------
__global__ void count_kernel(const int* __restrict__ ht, float* __restrict__ cnt, int m)
{
    int e = blockIdx.x * 256 + threadIdx.x;
    if (e < m) {
        atomicAdd(&cnt[ht[2 * e]],     1.0f);  // head (dst of back msg)
        atomicAdd(&cnt[ht[2 * e + 1]], 1.0f);  // tail (dst of fwd msg)
    }
}

// ---------------------------------------------------------------------------
// edge_kernel: per block of 32 edges:
//   1. stage triple = [H[h] | E | H[t]] (32 x 384 f32) into LDS
//   2. eu = leaky(triple @ W_eu + b_eu); en = LN(eu + E)  -> LDS + global Eout
//   3. mf = [H[h]|en] @ W_fwd + b_fwd ; mb = [H[t]|en] @ W_back + b_back
//   4. atomicAdd mf into agg[t], mb into agg[h]
// Thread layout for GEMMs: tid -> (c = tid&127 output column, eq = tid>>7),
// each thread accumulates 16 edges x 1 column.
// ---------------------------------------------------------------------------
__global__ __launch_bounds__(256, 2)
void edge_kernel(const float* __restrict__ H, const float* __restrict__ Ein,
                 float* __restrict__ Eout, const int* __restrict__ ht,
                 const float* __restrict__ Weu, const float* __restrict__ beu,
                 const float* __restrict__ lneg, const float* __restrict__ lneb,
                 const float* __restrict__ Wf, const float* __restrict__ bfw,
                 const float* __restrict__ Wb, const float* __restrict__ bbw,
                 float* __restrict__ agg)
{
    __shared__ float trip[EPB][3 * D];   // 48 KB
    __shared__ float en[EPB][D];         // 16 KB  (total 64 KB exactly)

    const int tid = threadIdx.x;
    const int e0  = blockIdx.x * EPB;

    // ---- stage triple rows (float4 granularity: 32 edges * 96 float4) ----
    for (int idx = tid; idx < EPB * 96; idx += 256) {
        int i   = idx / 96;
        int q   = idx - i * 96;
        int seg = q >> 5;        // 0 = head, 1 = E, 2 = tail
        int off = q & 31;        // float4 index within 128 floats
        int e   = e0 + i;
        const float* src;
        if (seg == 0)      src = H   + (size_t)ht[2 * e]     * D;
        else if (seg == 2) src = H   + (size_t)ht[2 * e + 1] * D;
        else               src = Ein + (size_t)e             * D;
        ((float4*)&trip[i][seg * D])[off] = ((const float4*)src)[off];
    }
    __syncthreads();

    const int c  = tid & 127;
    const int eq = tid >> 7;     // 0 or 1: which 16-edge group

    // ---------------- GEMM1: eu = triple(384) @ W_eu -> (32 x 128) ----------
    float acc[16];
#pragma unroll
    for (int i = 0; i < 16; ++i) acc[i] = 0.0f;

    const float* wp = Weu + c;
#pragma unroll 4
    for (int k = 0; k < 3 * D; k += 4) {
        float w0 = wp[(k + 0) * D];
        float w1 = wp[(k + 1) * D];
        float w2 = wp[(k + 2) * D];
        float w3 = wp[(k + 3) * D];
        const float* tb = &trip[eq * 16][k];
#pragma unroll
        for (int i = 0; i < 16; ++i) {
            float4 t4 = *(const float4*)(tb + i * (3 * D));
            acc[i] = fmaf(t4.x, w0, fmaf(t4.y, w1, fmaf(t4.z, w2, fmaf(t4.w, w3, acc[i]))));
        }
    }

    // bias + leaky + residual, park in en[][]
    {
        float be = beu[c];
#pragma unroll
        for (int i = 0; i < 16; ++i) {
            int ei = eq * 16 + i;
            float x = acc[i] + be;
            x = (x >= 0.0f) ? x : SLOPE * x;
            x += trip[ei][D + c];            // + E_old
            en[ei][c] = x;
        }
    }
    __syncthreads();

    // ---------------- LayerNorm per edge row (wave-parallel) ----------------
    {
        const int wave = tid >> 6, lane = tid & 63;
        float g0 = lneg[lane], g1 = lneg[lane + 64];
        float h0 = lneb[lane], h1 = lneb[lane + 64];
        for (int j = wave * 8; j < wave * 8 + 8; ++j) {
            float v0 = en[j][lane], v1 = en[j][lane + 64];
            float s  = v0 + v1;
            float ss = v0 * v0 + v1 * v1;
#pragma unroll
            for (int d = 1; d < 64; d <<= 1) {
                s  += __shfl_xor(s, d);
                ss += __shfl_xor(ss, d);
            }
            float mu  = s * (1.0f / 128.0f);
            float var = ss * (1.0f / 128.0f) - mu * mu;
            float rs  = rsqrtf(var + EPS);
            float o0 = (v0 - mu) * rs * g0 + h0;
            float o1 = (v1 - mu) * rs * g1 + h1;
            en[j][lane]      = o0;
            en[j][lane + 64] = o1;
            size_t ge = (size_t)(e0 + j) * D;
            Eout[ge + lane]      = o0;
            Eout[ge + lane + 64] = o1;
        }
    }
    __syncthreads();

    // ------------- GEMM2/3: mf = [head|en] @ Wf ; mb = [tail|en] @ Wb -------
    float af[16], ab[16];
#pragma unroll
    for (int i = 0; i < 16; ++i) { af[i] = 0.0f; ab[i] = 0.0f; }

    const float* wfp = Wf + c;
    const float* wbp = Wb + c;

    // half A: k in [0,128): fwd reads head (trip seg0), back reads tail (seg2)
    for (int k = 0; k < D; k += 4) {
        float f0 = wfp[(k + 0) * D], f1 = wfp[(k + 1) * D];
        float f2 = wfp[(k + 2) * D], f3 = wfp[(k + 3) * D];
        float g0 = wbp[(k + 0) * D], g1 = wbp[(k + 1) * D];
        float g2 = wbp[(k + 2) * D], g3 = wbp[(k + 3) * D];
#pragma unroll
        for (int i = 0; i < 16; ++i) {
            int ei = eq * 16 + i;
            float4 x = *(const float4*)&trip[ei][k];
            float4 y = *(const float4*)&trip[ei][2 * D + k];
            af[i] = fmaf(x.x, f0, fmaf(x.y, f1, fmaf(x.z, f2, fmaf(x.w, f3, af[i]))));
            ab[i] = fmaf(y.x, g0, fmaf(y.y, g1, fmaf(y.z, g2, fmaf(y.w, g3, ab[i]))));
        }
    }
    // half B: k in [128,256): both read en
    for (int k = 0; k < D; k += 4) {
        float f0 = wfp[(D + k + 0) * D], f1 = wfp[(D + k + 1) * D];
        float f2 = wfp[(D + k + 2) * D], f3 = wfp[(D + k + 3) * D];
        float g0 = wbp[(D + k + 0) * D], g1 = wbp[(D + k + 1) * D];
        float g2 = wbp[(D + k + 2) * D], g3 = wbp[(D + k + 3) * D];
#pragma unroll
        for (int i = 0; i < 16; ++i) {
            int ei = eq * 16 + i;
            float4 z = *(const float4*)&en[ei][k];
            af[i] = fmaf(z.x, f0, fmaf(z.y, f1, fmaf(z.z, f2, fmaf(z.w, f3, af[i]))));
            ab[i] = fmaf(z.x, g0, fmaf(z.y, g1, fmaf(z.z, g2, fmaf(z.w, g3, ab[i]))));
        }
    }

    // ---------------- scatter messages (mean numerator) ---------------------
    {
        float bfc = bfw[c], bbc = bbw[c];
#pragma unroll
        for (int i = 0; i < 16; ++i) {
            int e = e0 + eq * 16 + i;
            int hd = ht[2 * e];
            int td = ht[2 * e + 1];
            atomicAdd(&agg[(size_t)td * D + c], af[i] + bfc);  // fwd -> tail
            atomicAdd(&agg[(size_t)hd * D + c], ab[i] + bbc);  // back -> head
        }
    }
}

// ---------------------------------------------------------------------------
// node_kernel: H = LN(leaky(agg / max(cnt,1)) + H). One wave per node.
// ---------------------------------------------------------------------------
__global__ __launch_bounds__(256)
void node_kernel(const float* __restrict__ Hin, const float* __restrict__ agg,
                 const float* __restrict__ cnt, const float* __restrict__ g,
                 const float* __restrict__ b, float* __restrict__ Hout, int n)
{
    const int wave = threadIdx.x >> 6, lane = threadIdx.x & 63;
    const int node = blockIdx.x * 4 + wave;
    if (node >= n) return;

    float inv = 1.0f / fmaxf(cnt[node], 1.0f);
    size_t base = (size_t)node * D;

    float a0 = agg[base + lane] * inv;
    float a1 = agg[base + lane + 64] * inv;
    a0 = (a0 >= 0.0f) ? a0 : SLOPE * a0;
    a1 = (a1 >= 0.0f) ? a1 : SLOPE * a1;
    float x0 = a0 + Hin[base + lane];
    float x1 = a1 + Hin[base + lane + 64];

    float s = x0 + x1, ss = x0 * x0 + x1 * x1;
#pragma unroll
    for (int d = 1; d < 64; d <<= 1) {
        s  += __shfl_xor(s, d);
        ss += __shfl_xor(ss, d);
    }
    float mu  = s * (1.0f / 128.0f);
    float var = ss * (1.0f / 128.0f) - mu * mu;
    float rs  = rsqrtf(var + EPS);

    Hout[base + lane]      = (x0 - mu) * rs * g[lane]      + b[lane];
    Hout[base + lane + 64] = (x1 - mu) * rs * g[lane + 64] + b[lane + 64];
}

// ---------------------------------------------------------------------------
extern "C" void kernel_launch(void* const* d_in, const int* in_sizes, int n_in,
                              void* d_out, int out_size, void* d_ws, size_t ws_size,
                              hipStream_t stream)
{
    const float* H0   = (const float*)d_in[0];
    const float* E0   = (const float*)d_in[1];
    const int*   ht   = (const int*)d_in[2];
    // d_in[3] = queries (unused by reference)
    const float* Weu  = (const float*)d_in[4];
    const float* beu  = (const float*)d_in[5];
    const float* lneg = (const float*)d_in[6];
    const float* lneb = (const float*)d_in[7];
    const float* Wf   = (const float*)d_in[8];
    const float* bfw  = (const float*)d_in[9];
    const float* Wb   = (const float*)d_in[10];
    const float* bbw  = (const float*)d_in[11];
    const float* lnhg = (const float*)d_in[12];
    const float* lnhb = (const float*)d_in[13];

    float* Hout = (float*)d_out;

    // workspace layout
    char*  ws   = (char*)d_ws;
    float* agg  = (float*)ws;                                   // N*128 f32
    float* cnt  = (float*)(ws + (size_t)N_NODES * D * 4);       // N f32
    float* Ebuf = (float*)(ws + (size_t)N_NODES * D * 4 + (size_t)N_NODES * 4);  // M*128 f32

    // degree counts (same for both layers)
    hipMemsetAsync(cnt, 0, (size_t)N_NODES * sizeof(float), stream);
    count_kernel<<<(M_EDGES + 255) / 256, 256, 0, stream>>>(ht, cnt, M_EDGES);

    for (int l = 0; l < 2; ++l) {
        const float* Hin = (l == 0) ? H0 : Hout;
        const float* Ein = (l == 0) ? E0 : Ebuf;   // layer 1 updates Ebuf in place (per-edge rows)

        hipMemsetAsync(agg, 0, (size_t)N_NODES * D * sizeof(float), stream);

        edge_kernel<<<M_EDGES / EPB, 256, 0, stream>>>(
            Hin, Ein, Ebuf, ht,
            Weu + (size_t)l * 3 * D * D, beu + (size_t)l * D,
            lneg + (size_t)l * D, lneb + (size_t)l * D,
            Wf + (size_t)l * 2 * D * D, bfw + (size_t)l * D,
            Wb + (size_t)l * 2 * D * D, bbw + (size_t)l * D,
            agg);

        node_kernel<<<(N_NODES + 3) / 4, 256, 0, stream>>>(
            Hin, agg, cnt, lnhg + (size_t)l * D, lnhb + (size_t)l * D, Hout, N_NODES);
    }
}

// Round 2
// 1483.782 us; speedup vs baseline: 4.3648x; 4.3648x over previous
//
#include <hip/hip_runtime.h>

#define N_NODES 100000
#define M_EDGES 500000
#define D 128
#define EPB 64
#define SLOPE 0.01f
#define EPS 1e-5f

typedef __attribute__((ext_vector_type(8))) short bf16x8;
typedef __attribute__((ext_vector_type(4))) float f32x4;

__device__ __forceinline__ unsigned short f2bf(float f) {
    union { float f; unsigned u; } v; v.f = f;
    unsigned r = v.u + 0x7FFF + ((v.u >> 16) & 1);   // RNE
    return (unsigned short)(r >> 16);
}
__device__ __forceinline__ float bf2f(unsigned short u) {
    union { unsigned u; float f; } v; v.u = ((unsigned)u) << 16; return v.f;
}

// ---------------------------------------------------------------------------
// Weight pre-convert: fp32 [L][K][128] -> bf16 fragment-major [L][K/32][8][64][8]
// value(l,kk,nt,lane,j) = W[l][kk*32 + 8*(lane>>4) + j][nt*16 + (lane&15)]
// ---------------------------------------------------------------------------
__global__ void wconv_kernel(const float* __restrict__ src, unsigned short* __restrict__ dst,
                             int K, int total)
{
    int i = blockIdx.x * 256 + threadIdx.x;
    if (i >= total) return;
    int layer_sz = K * 128;
    int l = i / layer_sz;
    int r = i - l * layer_sz;
    int j    = r & 7;
    int lane = (r >> 3) & 63;
    int nt   = (r >> 9) & 7;
    int kk   = r >> 12;
    int row  = kk * 32 + ((lane >> 4) << 3) + j;
    int col  = nt * 16 + (lane & 15);
    dst[i] = f2bf(src[(size_t)l * layer_sz + row * 128 + col]);
}

__global__ void count_kernel(const int* __restrict__ ht, float* __restrict__ cnt, int m)
{
    int e = blockIdx.x * 256 + threadIdx.x;
    if (e < m) {
        atomicAdd(&cnt[ht[2 * e]],     1.0f);
        atomicAdd(&cnt[ht[2 * e + 1]], 1.0f);
    }
}

// ---------------------------------------------------------------------------
// Fused MFMA edge kernel. 64 edges/block, 4 waves x 16 edges.
// LDS: trip bf16 [64][384] (XOR-swizzled) | en bf16 [64][128] (XOR-swizzled)
//      | bstage 2 x 8192 B double-buffered W k-slices.  Total 80 KB.
// ---------------------------------------------------------------------------
template <bool E_BF16, bool WRITE_E>
__global__ __launch_bounds__(256, 2)
void edge_mfma_kernel(const float* __restrict__ H,
                      const float* __restrict__ Ef,
                      const unsigned short* __restrict__ Ebf,
                      unsigned short* __restrict__ Eout,
                      const int* __restrict__ ht,
                      const unsigned short* __restrict__ Weu,
                      const unsigned short* __restrict__ Wf,
                      const unsigned short* __restrict__ Wb,
                      const float* __restrict__ beu,
                      const float* __restrict__ lneg, const float* __restrict__ lneb,
                      const float* __restrict__ bfw, const float* __restrict__ bbw,
                      float* __restrict__ agg)
{
    __shared__ unsigned char smem[81920];
    unsigned char* trip = smem;            // 49152 B
    unsigned char* enb  = smem + 49152;    // 16384 B
    unsigned char* bst  = smem + 65536;    // 16384 B (2 x 8192)

    const int tid = threadIdx.x;
    const int e0  = blockIdx.x * EPB;
    const int wv  = tid >> 6;
    const int ln  = tid & 63;
    const int g   = ln >> 4;
    const int c15 = ln & 15;

    // ---------------- stage triple rows (bf16, XOR-swizzled) ----------------
    // H segments: 64 rows x 2 segs x 32 float4 units
    for (int u = tid; u < 4096; u += 256) {
        int off = u & 31, sg = (u >> 5) & 1, row = u >> 6;
        int e = e0 + row; if (e >= M_EDGES) e = e0;
        int node = ht[2 * e + sg];                 // sg=0 head, sg=1 tail
        float4 v = *(const float4*)(H + (size_t)node * D + off * 4);
        ushort4 p; p.x = f2bf(v.x); p.y = f2bf(v.y); p.z = f2bf(v.z); p.w = f2bf(v.w);
        int lin = row * 768 + sg * 512 + off * 8;  // head at 0, tail at 512
        *(ushort4*)(trip + (lin ^ ((row & 7) << 4))) = p;
    }
    // E segment: 64 rows x 32 units
    for (int u = tid; u < 2048; u += 256) {
        int off = u & 31, row = u >> 5;
        int e = e0 + row; if (e >= M_EDGES) e = e0;
        ushort4 p;
        if (E_BF16) {
            p = *(const ushort4*)(Ebf + (size_t)e * D + off * 4);
        } else {
            float4 v = *(const float4*)(Ef + (size_t)e * D + off * 4);
            p.x = f2bf(v.x); p.y = f2bf(v.y); p.z = f2bf(v.z); p.w = f2bf(v.w);
        }
        int lin = row * 768 + 256 + off * 8;
        *(ushort4*)(trip + (lin ^ ((row & 7) << 4))) = p;
    }
    __syncthreads();

    const int trip_row   = wv * 16 + c15;    // A-fragment row for this lane
    const int trip_rbyte = trip_row * 768;
    const int en_rbyte   = trip_row * 256;
    const int xorR       = (trip_row & 7) << 4;

    uint4 r0, r1;
    int buf;

    // ============================ GEMM1: eu = triple @ Weu ==================
    f32x4 acc[8];
#pragma unroll
    for (int nt = 0; nt < 8; ++nt) acc[nt] = (f32x4){0.f, 0.f, 0.f, 0.f};

    {   // prologue stage kk=0
        const uint4* gp = (const uint4*)Weu;
        r0 = gp[tid]; r1 = gp[tid + 256];
        uint4* lp = (uint4*)bst;
        lp[tid] = r0; lp[tid + 256] = r1;
    }
    __syncthreads();
    buf = 0;
    for (int kk = 0; kk < 12; ++kk) {
        if (kk < 11) {
            const uint4* gp = (const uint4*)(Weu + (kk + 1) * 4096);
            r0 = gp[tid]; r1 = gp[tid + 256];
        }
        bf16x8 a = *(const bf16x8*)(trip + ((trip_rbyte + kk * 64 + g * 16) ^ xorR));
#pragma unroll
        for (int nt = 0; nt < 8; ++nt) {
            bf16x8 b = *(const bf16x8*)(bst + buf * 8192 + nt * 1024 + ln * 16);
            acc[nt] = __builtin_amdgcn_mfma_f32_16x16x32_bf16(a, b, acc[nt], 0, 0, 0);
        }
        if (kk < 11) {
            uint4* lp = (uint4*)(bst + (buf ^ 1) * 8192);
            lp[tid] = r0; lp[tid + 256] = r1;
        }
        __syncthreads();
        buf ^= 1;
    }

    // ================= bias + leaky + residual + LayerNorm ==================
    {
        float s[4] = {0.f,0.f,0.f,0.f}, ss[4] = {0.f,0.f,0.f,0.f};
        float beu_v[8];
#pragma unroll
        for (int nt = 0; nt < 8; ++nt) beu_v[nt] = beu[nt * 16 + c15];
#pragma unroll
        for (int nt = 0; nt < 8; ++nt) {
#pragma unroll
            for (int r = 0; r < 4; ++r) {
                int row = wv * 16 + g * 4 + r;
                float x = acc[nt][r] + beu_v[nt];
                x = (x >= 0.f) ? x : SLOPE * x;
                int lin = row * 768 + 256 + (nt * 16 + c15) * 2;
                x += bf2f(*(const unsigned short*)(trip + (lin ^ ((row & 7) << 4))));
                acc[nt][r] = x;
                s[r] += x; ss[r] += x * x;
            }
        }
#pragma unroll
        for (int m = 1; m < 16; m <<= 1) {
#pragma unroll
            for (int r = 0; r < 4; ++r) {
                s[r]  += __shfl_xor(s[r],  m);
                ss[r] += __shfl_xor(ss[r], m);
            }
        }
        float lg[8], lb[8];
#pragma unroll
        for (int nt = 0; nt < 8; ++nt) { lg[nt] = lneg[nt*16+c15]; lb[nt] = lneb[nt*16+c15]; }
        float mu[4], rs[4];
#pragma unroll
        for (int r = 0; r < 4; ++r) {
            mu[r] = s[r] * (1.0f / 128.0f);
            float var = ss[r] * (1.0f / 128.0f) - mu[r] * mu[r];
            rs[r] = rsqrtf(var + EPS);
        }
#pragma unroll
        for (int nt = 0; nt < 8; ++nt) {
#pragma unroll
            for (int r = 0; r < 4; ++r) {
                int row = wv * 16 + g * 4 + r;
                float xn = (acc[nt][r] - mu[r]) * rs[r] * lg[nt] + lb[nt];
                int lin = row * 256 + (nt * 16 + c15) * 2;
                *(unsigned short*)(enb + (lin ^ ((row & 7) << 4))) = f2bf(xn);
            }
        }
    }
    __syncthreads();

    // -------- write E_new (bf16) to global for the next layer ---------------
    if (WRITE_E) {
        int valid = M_EDGES - e0; if (valid > EPB) valid = EPB;
        for (int u = tid; u < 2048; u += 256) {
            int off = u & 31, row = u >> 5;
            if (row < valid) {
                int lin = row * 256 + off * 8;
                ushort4 p = *(const ushort4*)(enb + (lin ^ ((row & 7) << 4)));
                *(ushort4*)(Eout + (size_t)(e0 + row) * D + off * 4) = p;
            }
        }
    }

    // ==================== GEMM2: mf = [head|en] @ Wf ========================
    f32x4 acc2[8];
#pragma unroll
    for (int nt = 0; nt < 8; ++nt) acc2[nt] = (f32x4){0.f, 0.f, 0.f, 0.f};
    {
        const uint4* gp = (const uint4*)Wf;
        r0 = gp[tid]; r1 = gp[tid + 256];
        uint4* lp = (uint4*)bst;
        lp[tid] = r0; lp[tid + 256] = r1;
    }
    __syncthreads();
    buf = 0;
    for (int kk = 0; kk < 8; ++kk) {
        if (kk < 7) {
            const uint4* gp = (const uint4*)(Wf + (kk + 1) * 4096);
            r0 = gp[tid]; r1 = gp[tid + 256];
        }
        bf16x8 a;
        if (kk < 4) a = *(const bf16x8*)(trip + ((trip_rbyte + kk * 64 + g * 16) ^ xorR));
        else        a = *(const bf16x8*)(enb  + ((en_rbyte + (kk - 4) * 64 + g * 16) ^ xorR));
#pragma unroll
        for (int nt = 0; nt < 8; ++nt) {
            bf16x8 b = *(const bf16x8*)(bst + buf * 8192 + nt * 1024 + ln * 16);
            acc2[nt] = __builtin_amdgcn_mfma_f32_16x16x32_bf16(a, b, acc2[nt], 0, 0, 0);
        }
        if (kk < 7) {
            uint4* lp = (uint4*)(bst + (buf ^ 1) * 8192);
            lp[tid] = r0; lp[tid + 256] = r1;
        }
        __syncthreads();
        buf ^= 1;
    }
    {   // scatter fwd messages -> tail
        float bf_v[8];
#pragma unroll
        for (int nt = 0; nt < 8; ++nt) bf_v[nt] = bfw[nt * 16 + c15];
#pragma unroll
        for (int r = 0; r < 4; ++r) {
            int e = e0 + wv * 16 + g * 4 + r;
            if (e < M_EDGES) {
                int dst = ht[2 * e + 1];
                float* ap = agg + (size_t)dst * D + c15;
#pragma unroll
                for (int nt = 0; nt < 8; ++nt)
                    atomicAdd(ap + nt * 16, acc2[nt][r] + bf_v[nt]);
            }
        }
    }
    __syncthreads();

    // ==================== GEMM3: mb = [tail|en] @ Wb ========================
#pragma unroll
    for (int nt = 0; nt < 8; ++nt) acc2[nt] = (f32x4){0.f, 0.f, 0.f, 0.f};
    {
        const uint4* gp = (const uint4*)Wb;
        r0 = gp[tid]; r1 = gp[tid + 256];
        uint4* lp = (uint4*)bst;
        lp[tid] = r0; lp[tid + 256] = r1;
    }
    __syncthreads();
    buf = 0;
    for (int kk = 0; kk < 8; ++kk) {
        if (kk < 7) {
            const uint4* gp = (const uint4*)(Wb + (kk + 1) * 4096);
            r0 = gp[tid]; r1 = gp[tid + 256];
        }
        bf16x8 a;
        if (kk < 4) a = *(const bf16x8*)(trip + ((trip_rbyte + 512 + kk * 64 + g * 16) ^ xorR));
        else        a = *(const bf16x8*)(enb  + ((en_rbyte + (kk - 4) * 64 + g * 16) ^ xorR));
#pragma unroll
        for (int nt = 0; nt < 8; ++nt) {
            bf16x8 b = *(const bf16x8*)(bst + buf * 8192 + nt * 1024 + ln * 16);
            acc2[nt] = __builtin_amdgcn_mfma_f32_16x16x32_bf16(a, b, acc2[nt], 0, 0, 0);
        }
        if (kk < 7) {
            uint4* lp = (uint4*)(bst + (buf ^ 1) * 8192);
            lp[tid] = r0; lp[tid + 256] = r1;
        }
        __syncthreads();
        buf ^= 1;
    }
    {   // scatter back messages -> head
        float bb_v[8];
#pragma unroll
        for (int nt = 0; nt < 8; ++nt) bb_v[nt] = bbw[nt * 16 + c15];
#pragma unroll
        for (int r = 0; r < 4; ++r) {
            int e = e0 + wv * 16 + g * 4 + r;
            if (e < M_EDGES) {
                int dst = ht[2 * e];
                float* ap = agg + (size_t)dst * D + c15;
#pragma unroll
                for (int nt = 0; nt < 8; ++nt)
                    atomicAdd(ap + nt * 16, acc2[nt][r] + bb_v[nt]);
            }
        }
    }
}

// ---------------------------------------------------------------------------
// node_kernel: H = LN(leaky(agg / max(cnt,1)) + H). One wave per node.
// ---------------------------------------------------------------------------
__global__ __launch_bounds__(256)
void node_kernel(const float* __restrict__ Hin, const float* __restrict__ agg,
                 const float* __restrict__ cnt, const float* __restrict__ g,
                 const float* __restrict__ b, float* __restrict__ Hout, int n)
{
    const int wave = threadIdx.x >> 6, lane = threadIdx.x & 63;
    const int node = blockIdx.x * 4 + wave;
    if (node >= n) return;

    float inv = 1.0f / fmaxf(cnt[node], 1.0f);
    size_t base = (size_t)node * D;

    float a0 = agg[base + lane] * inv;
    float a1 = agg[base + lane + 64] * inv;
    a0 = (a0 >= 0.0f) ? a0 : SLOPE * a0;
    a1 = (a1 >= 0.0f) ? a1 : SLOPE * a1;
    float x0 = a0 + Hin[base + lane];
    float x1 = a1 + Hin[base + lane + 64];

    float s = x0 + x1, ss = x0 * x0 + x1 * x1;
#pragma unroll
    for (int d = 1; d < 64; d <<= 1) {
        s  += __shfl_xor(s, d);
        ss += __shfl_xor(ss, d);
    }
    float mu  = s * (1.0f / 128.0f);
    float var = ss * (1.0f / 128.0f) - mu * mu;
    float rs  = rsqrtf(var + EPS);

    Hout[base + lane]      = (x0 - mu) * rs * g[lane]      + b[lane];
    Hout[base + lane + 64] = (x1 - mu) * rs * g[lane + 64] + b[lane + 64];
}

// ---------------------------------------------------------------------------
extern "C" void kernel_launch(void* const* d_in, const int* in_sizes, int n_in,
                              void* d_out, int out_size, void* d_ws, size_t ws_size,
                              hipStream_t stream)
{
    const float* H0   = (const float*)d_in[0];
    const float* E0   = (const float*)d_in[1];
    const int*   ht   = (const int*)d_in[2];
    const float* Weu  = (const float*)d_in[4];
    const float* beu  = (const float*)d_in[5];
    const float* lneg = (const float*)d_in[6];
    const float* lneb = (const float*)d_in[7];
    const float* Wf   = (const float*)d_in[8];
    const float* bfw  = (const float*)d_in[9];
    const float* Wb   = (const float*)d_in[10];
    const float* bbw  = (const float*)d_in[11];
    const float* lnhg = (const float*)d_in[12];
    const float* lnhb = (const float*)d_in[13];

    float* Hout = (float*)d_out;

    // workspace layout (16B-aligned offsets)
    char* ws = (char*)d_ws;
    float*          agg    = (float*)ws;                               // 51,200,000 B
    float*          cnt    = (float*)(ws + 51200000);                  //    400,000 B
    unsigned short* Ebuf   = (unsigned short*)(ws + 51600000);         // 128,000,000 B
    unsigned short* Weu_sw = (unsigned short*)(ws + 179600000);        //    196,608 B
    unsigned short* Wf_sw  = (unsigned short*)(ws + 179796608);        //    131,072 B
    unsigned short* Wb_sw  = (unsigned short*)(ws + 179927680);        //    131,072 B

    // weight conversion to swizzled bf16
    wconv_kernel<<<(2*384*128 + 255)/256, 256, 0, stream>>>(Weu, Weu_sw, 384, 2*384*128);
    wconv_kernel<<<(2*256*128 + 255)/256, 256, 0, stream>>>(Wf,  Wf_sw,  256, 2*256*128);
    wconv_kernel<<<(2*256*128 + 255)/256, 256, 0, stream>>>(Wb,  Wb_sw,  256, 2*256*128);

    hipMemsetAsync(cnt, 0, (size_t)N_NODES * sizeof(float), stream);
    count_kernel<<<(M_EDGES + 255) / 256, 256, 0, stream>>>(ht, cnt, M_EDGES);

    const int eblocks = (M_EDGES + EPB - 1) / EPB;

    for (int l = 0; l < 2; ++l) {
        const float* Hin = (l == 0) ? H0 : Hout;
        hipMemsetAsync(agg, 0, (size_t)N_NODES * D * sizeof(float), stream);

        if (l == 0) {
            edge_mfma_kernel<false, true><<<eblocks, 256, 0, stream>>>(
                Hin, E0, nullptr, Ebuf, ht,
                Weu_sw, Wf_sw, Wb_sw,
                beu, lneg, lneb, bfw, bbw, agg);
        } else {
            edge_mfma_kernel<true, false><<<eblocks, 256, 0, stream>>>(
                Hin, nullptr, Ebuf, nullptr, ht,
                Weu_sw + 49152, Wf_sw + 32768, Wb_sw + 32768,
                beu + D, lneg + D, lneb + D, bfw + D, bbw + D, agg);
        }

        node_kernel<<<(N_NODES + 3) / 4, 256, 0, stream>>>(
            Hin, agg, cnt, lnhg + (size_t)l * D, lnhb + (size_t)l * D, Hout, N_NODES);
    }
}

// Round 3
// 1403.135 us; speedup vs baseline: 4.6156x; 1.0575x over previous
//
#include <hip/hip_runtime.h>

#define N_NODES 100000
#define M_EDGES 500000
#define D 128
#define SLOPE 0.01f
#define EPS 1e-5f

typedef __attribute__((ext_vector_type(8))) short bf16x8;
typedef __attribute__((ext_vector_type(4))) float f32x4;

__device__ __forceinline__ unsigned short f2bf(float f) {
    union { float f; unsigned u; } v; v.f = f;
    unsigned r = v.u + 0x7FFF + ((v.u >> 16) & 1);   // RNE
    return (unsigned short)(r >> 16);
}
__device__ __forceinline__ float bf2f(unsigned short u) {
    union { unsigned u; float f; } v; v.u = ((unsigned)u) << 16; return v.f;
}
__device__ __forceinline__ uint4 pack8(float4 a, float4 b) {
    uint4 r;
    r.x = ((unsigned)f2bf(a.y) << 16) | f2bf(a.x);
    r.y = ((unsigned)f2bf(a.w) << 16) | f2bf(a.z);
    r.z = ((unsigned)f2bf(b.y) << 16) | f2bf(b.x);
    r.w = ((unsigned)f2bf(b.w) << 16) | f2bf(b.z);
    return r;
}
// packed bf16x2 atomic add (gfx950: global_atomic_pk_add_bf16)
__device__ __forceinline__ void atomic_pk_bf16(unsigned short* p, unsigned v) {
    asm volatile("global_atomic_pk_add_bf16 %0, %1, off" :: "v"(p), "v"(v) : "memory");
}

// ---------------------------------------------------------------------------
// Weight pre-convert: fp32 [L][K][128] -> bf16 fragment-major [L][K/32][8][64][8]
// value(l,kk,nt,lane,j) = W[l][kk*32 + 8*(lane>>4) + j][nt*16 + (lane&15)]
// ---------------------------------------------------------------------------
__global__ void wconv_kernel(const float* __restrict__ src, unsigned short* __restrict__ dst,
                             int K, int total)
{
    int i = blockIdx.x * 256 + threadIdx.x;
    if (i >= total) return;
    int layer_sz = K * 128;
    int l = i / layer_sz;
    int r = i - l * layer_sz;
    int j    = r & 7;
    int lane = (r >> 3) & 63;
    int nt   = (r >> 9) & 7;
    int kk   = r >> 12;
    int row  = kk * 32 + ((lane >> 4) << 3) + j;
    int col  = nt * 16 + (lane & 15);
    dst[i] = f2bf(src[(size_t)l * layer_sz + row * 128 + col]);
}

// H (f32) -> Hb (bf16), vector 8
__global__ void h2b_kernel(const float* __restrict__ src, unsigned short* __restrict__ dst, int total8)
{
    int i = blockIdx.x * 256 + threadIdx.x;
    if (i >= total8) return;
    float4 a = ((const float4*)src)[2 * i];
    float4 b = ((const float4*)src)[2 * i + 1];
    ((uint4*)dst)[i] = pack8(a, b);
}

__global__ void count_kernel(const int* __restrict__ ht, float* __restrict__ cnt, int m)
{
    int e = blockIdx.x * 256 + threadIdx.x;
    if (e < m) {
        atomicAdd(&cnt[ht[2 * e]],     1.0f);
        atomicAdd(&cnt[ht[2 * e + 1]], 1.0f);
    }
}

// ---------------------------------------------------------------------------
// Barrier-free fused edge kernel.
// 256 threads = 4 waves; each wave owns 32 edges (2 MFMA M-tiles of 16).
// A-fragments: gathered from global (Hb bf16) / per-wave LDS (E/en, swizzled).
// B-fragments: streamed global->reg (swizzled layout = coalesced 16B/lane),
//              double-buffered per k-step. No __syncthreads anywhere.
// ---------------------------------------------------------------------------
template <bool E_F32, bool WRITE_E>
__global__ __launch_bounds__(256, 2)
void edge_mfma_kernel(const unsigned short* __restrict__ Hb,
                      const float* __restrict__ E0,
                      const unsigned short* __restrict__ Ebf,
                      unsigned short* __restrict__ Eout,
                      const int* __restrict__ ht,
                      const unsigned short* __restrict__ Weu,
                      const unsigned short* __restrict__ Wf,
                      const unsigned short* __restrict__ Wb,
                      const float* __restrict__ beu,
                      const float* __restrict__ lneg, const float* __restrict__ lneb,
                      const float* __restrict__ bfw, const float* __restrict__ bbw,
                      unsigned short* __restrict__ agg)
{
    __shared__ unsigned char smem[32768];   // 4 waves x 8KB (E/en rows, swizzled)

    const int tid = threadIdx.x;
    const int wv  = tid >> 6;
    const int ln  = tid & 63;
    const int g   = ln >> 4;
    const int c15 = ln & 15;
    const int ew0 = blockIdx.x * 128 + wv * 32;
    if (ew0 >= M_EDGES) return;             // barrier-free: safe early exit

    unsigned char* en = smem + wv * 8192;

    // ---- stage this wave's 32 E rows into LDS (bf16, XOR-swizzled) ----
#pragma unroll
    for (int it = 0; it < 8; ++it) {
        int lin = it * 1024 + ln * 16;      // dest byte in [0,8192)
        int row = lin >> 8;
        int e   = ew0 + row;
        int es  = (e < M_EDGES) ? e : ew0;
        int elem = (lin & 255) >> 1;        // element offset within row
        uint4 pk;
        if (E_F32) {
            const float* s = E0 + (size_t)es * D + elem;
            pk = pack8(*(const float4*)s, *(const float4*)(s + 4));
        } else {
            pk = *(const uint4*)(Ebf + (size_t)es * D + elem);
        }
        *(uint4*)(en + (lin ^ ((row & 7) << 4))) = pk;
    }

    // ---- per-lane A-row pointers (lane's rows: c15 and c15+16) ----
    int eA0 = ew0 + c15;        if (eA0 >= M_EDGES) eA0 = M_EDGES - 1;
    int eA1 = ew0 + 16 + c15;   if (eA1 >= M_EDGES) eA1 = M_EDGES - 1;
    int2 htA0 = ((const int2*)ht)[eA0];
    int2 htA1 = ((const int2*)ht)[eA1];
    const unsigned short* hrow0 = Hb + (size_t)htA0.x * D;
    const unsigned short* hrow1 = Hb + (size_t)htA1.x * D;
    const unsigned short* trow0 = Hb + (size_t)htA0.y * D;
    const unsigned short* trow1 = Hb + (size_t)htA1.y * D;
    const int enoff0 = c15 * 256;
    const int enoff1 = (16 + c15) * 256;
    const int swz    = (c15 & 7) << 4;      // same for both m (16 doesn't touch &7)

    f32x4 acc[2][8];

    // =========================== GEMM1: triple(384) @ Weu ===================
#pragma unroll
    for (int m = 0; m < 2; ++m)
#pragma unroll
        for (int nt = 0; nt < 8; ++nt) acc[m][nt] = (f32x4){0.f, 0.f, 0.f, 0.f};

    {
        const uint4* Wg = (const uint4*)Weu;
        uint4 bc[8], bn[8];
        bf16x8 a0, a1, a0n, a1n;
        auto loadA = [&](int kk, int m) -> bf16x8 {
            if (kk < 4)
                return *(const bf16x8*)((m ? hrow1 : hrow0) + kk * 32 + g * 8);
            if (kk < 8)
                return *(const bf16x8*)(en + (((m ? enoff1 : enoff0) + (kk - 4) * 64 + g * 16) ^ swz));
            return *(const bf16x8*)((m ? trow1 : trow0) + (kk - 8) * 32 + g * 8);
        };
#pragma unroll
        for (int nt = 0; nt < 8; ++nt) bc[nt] = Wg[nt * 64 + ln];
        a0 = loadA(0, 0); a1 = loadA(0, 1);
#pragma unroll
        for (int kk = 0; kk < 12; ++kk) {
            if (kk < 11) {
#pragma unroll
                for (int nt = 0; nt < 8; ++nt) bn[nt] = Wg[(kk + 1) * 512 + nt * 64 + ln];
                a0n = loadA(kk + 1, 0); a1n = loadA(kk + 1, 1);
            }
#pragma unroll
            for (int nt = 0; nt < 8; ++nt) {
                bf16x8 b = *(const bf16x8*)&bc[nt];
                acc[0][nt] = __builtin_amdgcn_mfma_f32_16x16x32_bf16(a0, b, acc[0][nt], 0, 0, 0);
                acc[1][nt] = __builtin_amdgcn_mfma_f32_16x16x32_bf16(a1, b, acc[1][nt], 0, 0, 0);
            }
            if (kk < 11) {
#pragma unroll
                for (int nt = 0; nt < 8; ++nt) bc[nt] = bn[nt];
                a0 = a0n; a1 = a1n;
            }
        }
    }

    // ============ bias + leaky + residual + LayerNorm -> en (LDS) ===========
    {
        float be[8], lg[8], lb[8];
#pragma unroll
        for (int nt = 0; nt < 8; ++nt) {
            be[nt] = beu[nt * 16 + c15];
            lg[nt] = lneg[nt * 16 + c15];
            lb[nt] = lneb[nt * 16 + c15];
        }
#pragma unroll
        for (int m = 0; m < 2; ++m) {
            float s[4] = {0.f,0.f,0.f,0.f}, ss[4] = {0.f,0.f,0.f,0.f};
#pragma unroll
            for (int nt = 0; nt < 8; ++nt) {
#pragma unroll
                for (int r = 0; r < 4; ++r) {
                    int row = m * 16 + g * 4 + r;
                    float x = acc[m][nt][r] + be[nt];
                    x = (x >= 0.f) ? x : SLOPE * x;
                    int lin = row * 256 + (nt * 16 + c15) * 2;
                    x += bf2f(*(const unsigned short*)(en + (lin ^ ((row & 7) << 4))));
                    acc[m][nt][r] = x;
                    s[r] += x; ss[r] += x * x;
                }
            }
#pragma unroll
            for (int d = 1; d < 16; d <<= 1) {
#pragma unroll
                for (int r = 0; r < 4; ++r) {
                    s[r]  += __shfl_xor(s[r],  d);
                    ss[r] += __shfl_xor(ss[r], d);
                }
            }
            float mu[4], rs[4];
#pragma unroll
            for (int r = 0; r < 4; ++r) {
                mu[r] = s[r] * (1.0f / 128.0f);
                float var = ss[r] * (1.0f / 128.0f) - mu[r] * mu[r];
                rs[r] = rsqrtf(var + EPS);
            }
#pragma unroll
            for (int nt = 0; nt < 8; ++nt) {
#pragma unroll
                for (int r = 0; r < 4; ++r) {
                    int row = m * 16 + g * 4 + r;
                    float xn = (acc[m][nt][r] - mu[r]) * rs[r] * lg[nt] + lb[nt];
                    int lin = row * 256 + (nt * 16 + c15) * 2;
                    *(unsigned short*)(en + (lin ^ ((row & 7) << 4))) = f2bf(xn);
                }
            }
        }
    }

    // ---- write E_new to global (layer 0 only) ----
    if (WRITE_E) {
#pragma unroll
        for (int it = 0; it < 8; ++it) {
            int lin = it * 1024 + ln * 16;
            int row = lin >> 8;
            int e   = ew0 + row;
            if (e < M_EDGES)
                *(uint4*)(Eout + (size_t)e * D + ((lin & 255) >> 1)) =
                    *(const uint4*)(en + (lin ^ ((row & 7) << 4)));
        }
    }

    // =================== GEMM2 ([head|en] @ Wf) + GEMM3 ([tail|en] @ Wb) ====
#pragma unroll
    for (int pass = 0; pass < 2; ++pass) {
        const uint4* Wg = (const uint4*)(pass == 0 ? Wf : Wb);
        const unsigned short* r0 = pass == 0 ? hrow0 : trow0;
        const unsigned short* r1 = pass == 0 ? hrow1 : trow1;
#pragma unroll
        for (int m = 0; m < 2; ++m)
#pragma unroll
            for (int nt = 0; nt < 8; ++nt) acc[m][nt] = (f32x4){0.f, 0.f, 0.f, 0.f};

        {
            uint4 bc[8], bn[8];
            bf16x8 a0, a1, a0n, a1n;
            auto loadA = [&](int kk, int m) -> bf16x8 {
                if (kk < 4)
                    return *(const bf16x8*)((m ? r1 : r0) + kk * 32 + g * 8);
                return *(const bf16x8*)(en + (((m ? enoff1 : enoff0) + (kk - 4) * 64 + g * 16) ^ swz));
            };
#pragma unroll
            for (int nt = 0; nt < 8; ++nt) bc[nt] = Wg[nt * 64 + ln];
            a0 = loadA(0, 0); a1 = loadA(0, 1);
#pragma unroll
            for (int kk = 0; kk < 8; ++kk) {
                if (kk < 7) {
#pragma unroll
                    for (int nt = 0; nt < 8; ++nt) bn[nt] = Wg[(kk + 1) * 512 + nt * 64 + ln];
                    a0n = loadA(kk + 1, 0); a1n = loadA(kk + 1, 1);
                }
#pragma unroll
                for (int nt = 0; nt < 8; ++nt) {
                    bf16x8 b = *(const bf16x8*)&bc[nt];
                    acc[0][nt] = __builtin_amdgcn_mfma_f32_16x16x32_bf16(a0, b, acc[0][nt], 0, 0, 0);
                    acc[1][nt] = __builtin_amdgcn_mfma_f32_16x16x32_bf16(a1, b, acc[1][nt], 0, 0, 0);
                }
                if (kk < 7) {
#pragma unroll
                    for (int nt = 0; nt < 8; ++nt) bc[nt] = bn[nt];
                    a0 = a0n; a1 = a1n;
                }
            }
        }

        // ---- scatter: packed bf16x2 atomics (even lanes nt0-3, odd nt4-7) --
        {
            const float* bias = pass == 0 ? bfw : bbw;
            float bv[8];
#pragma unroll
            for (int nt = 0; nt < 8; ++nt) bv[nt] = bias[nt * 16 + c15];
#pragma unroll
            for (int m = 0; m < 2; ++m) {
#pragma unroll
                for (int r = 0; r < 4; ++r) {
                    int e = ew0 + m * 16 + g * 4 + r;
                    bool val = (e < M_EDGES);
                    int2 p = ((const int2*)ht)[val ? e : 0];
                    int dst = pass == 0 ? p.y : p.x;       // fwd->tail, back->head
                    unsigned short* base = agg + (size_t)dst * D + (c15 & ~1);
#pragma unroll
                    for (int nt = 0; nt < 8; ++nt) {
                        float v = acc[m][nt][r] + bv[nt];
                        float o = __shfl_xor(v, 1);
                        float lo = (ln & 1) ? o : v;
                        float hi = (ln & 1) ? v : o;
                        unsigned pk = ((unsigned)f2bf(hi) << 16) | f2bf(lo);
                        if (val && ((ln & 1) == (nt >> 2)))
                            atomic_pk_bf16(base + nt * 16, pk);
                    }
                }
            }
        }
    }
}

// ---------------------------------------------------------------------------
// node_kernel: H = LN(leaky(agg/max(cnt,1)) + H); writes f32 Hout + bf16 Hb.
// ---------------------------------------------------------------------------
__global__ __launch_bounds__(256)
void node_kernel(const float* __restrict__ Hin, const unsigned short* __restrict__ aggb,
                 const float* __restrict__ cnt, const float* __restrict__ g,
                 const float* __restrict__ b, float* __restrict__ Hout,
                 unsigned short* __restrict__ Hb, int n)
{
    const int wave = threadIdx.x >> 6, lane = threadIdx.x & 63;
    const int node = blockIdx.x * 4 + wave;
    if (node >= n) return;

    float inv = 1.0f / fmaxf(cnt[node], 1.0f);
    size_t base = (size_t)node * D;

    float a0 = bf2f(aggb[base + lane]) * inv;
    float a1 = bf2f(aggb[base + lane + 64]) * inv;
    a0 = (a0 >= 0.0f) ? a0 : SLOPE * a0;
    a1 = (a1 >= 0.0f) ? a1 : SLOPE * a1;
    float x0 = a0 + Hin[base + lane];
    float x1 = a1 + Hin[base + lane + 64];

    float s = x0 + x1, ss = x0 * x0 + x1 * x1;
#pragma unroll
    for (int d = 1; d < 64; d <<= 1) {
        s  += __shfl_xor(s, d);
        ss += __shfl_xor(ss, d);
    }
    float mu  = s * (1.0f / 128.0f);
    float var = ss * (1.0f / 128.0f) - mu * mu;
    float rs  = rsqrtf(var + EPS);

    float o0 = (x0 - mu) * rs * g[lane]      + b[lane];
    float o1 = (x1 - mu) * rs * g[lane + 64] + b[lane + 64];
    Hout[base + lane]      = o0;
    Hout[base + lane + 64] = o1;
    Hb[base + lane]        = f2bf(o0);
    Hb[base + lane + 64]   = f2bf(o1);
}

// ---------------------------------------------------------------------------
extern "C" void kernel_launch(void* const* d_in, const int* in_sizes, int n_in,
                              void* d_out, int out_size, void* d_ws, size_t ws_size,
                              hipStream_t stream)
{
    const float* H0   = (const float*)d_in[0];
    const float* E0   = (const float*)d_in[1];
    const int*   ht   = (const int*)d_in[2];
    const float* Weu  = (const float*)d_in[4];
    const float* beu  = (const float*)d_in[5];
    const float* lneg = (const float*)d_in[6];
    const float* lneb = (const float*)d_in[7];
    const float* Wf   = (const float*)d_in[8];
    const float* bfw  = (const float*)d_in[9];
    const float* Wb   = (const float*)d_in[10];
    const float* bbw  = (const float*)d_in[11];
    const float* lnhg = (const float*)d_in[12];
    const float* lnhb = (const float*)d_in[13];

    float* Hout = (float*)d_out;

    // workspace layout
    char* ws = (char*)d_ws;
    unsigned short* aggb   = (unsigned short*)ws;                   //  25,600,000
    float*          cnt    = (float*)(ws + 25600000);               //     400,000
    unsigned short* Ebuf   = (unsigned short*)(ws + 26000000);      // 128,000,000
    unsigned short* Hb     = (unsigned short*)(ws + 154000000);     //  25,600,000
    unsigned short* Weu_sw = (unsigned short*)(ws + 179600000);     //     196,608
    unsigned short* Wf_sw  = (unsigned short*)(ws + 179796608);     //     131,072
    unsigned short* Wb_sw  = (unsigned short*)(ws + 179927680);     //     131,072

    wconv_kernel<<<(2*384*128 + 255)/256, 256, 0, stream>>>(Weu, Weu_sw, 384, 2*384*128);
    wconv_kernel<<<(2*256*128 + 255)/256, 256, 0, stream>>>(Wf,  Wf_sw,  256, 2*256*128);
    wconv_kernel<<<(2*256*128 + 255)/256, 256, 0, stream>>>(Wb,  Wb_sw,  256, 2*256*128);
    h2b_kernel<<<(N_NODES * D / 8 + 255)/256, 256, 0, stream>>>(H0, Hb, N_NODES * D / 8);

    hipMemsetAsync(cnt, 0, (size_t)N_NODES * sizeof(float), stream);
    count_kernel<<<(M_EDGES + 255) / 256, 256, 0, stream>>>(ht, cnt, M_EDGES);

    const int eblocks = (M_EDGES + 127) / 128;

    for (int l = 0; l < 2; ++l) {
        const float* Hin = (l == 0) ? H0 : Hout;
        hipMemsetAsync(aggb, 0, (size_t)N_NODES * D * sizeof(unsigned short), stream);

        if (l == 0) {
            edge_mfma_kernel<true, true><<<eblocks, 256, 0, stream>>>(
                Hb, E0, nullptr, Ebuf, ht,
                Weu_sw, Wf_sw, Wb_sw,
                beu, lneg, lneb, bfw, bbw, aggb);
        } else {
            edge_mfma_kernel<false, false><<<eblocks, 256, 0, stream>>>(
                Hb, nullptr, Ebuf, nullptr, ht,
                Weu_sw + 49152, Wf_sw + 32768, Wb_sw + 32768,
                beu + D, lneg + D, lneb + D, bfw + D, bbw + D, aggb);
        }

        node_kernel<<<(N_NODES + 3) / 4, 256, 0, stream>>>(
            Hin, aggb, cnt, lnhg + (size_t)l * D, lnhb + (size_t)l * D, Hout, Hb, N_NODES);
    }
}

// Round 4
// 1252.323 us; speedup vs baseline: 5.1715x; 1.1204x over previous
//
#include <hip/hip_runtime.h>

#define N_NODES 100000
#define M_EDGES 500000
#define D 128
#define SLOPE 0.01f
#define EPS 1e-5f

typedef __attribute__((ext_vector_type(8))) short bf16x8;
typedef __attribute__((ext_vector_type(4))) float f32x4;

__device__ __forceinline__ unsigned short f2bf(float f) {
    union { float f; unsigned u; } v; v.f = f;
    unsigned r = v.u + 0x7FFF + ((v.u >> 16) & 1);   // RNE
    return (unsigned short)(r >> 16);
}
__device__ __forceinline__ float bf2f(unsigned short u) {
    union { unsigned u; float f; } v; v.u = ((unsigned)u) << 16; return v.f;
}
__device__ __forceinline__ uint4 pack8(float4 a, float4 b) {
    uint4 r;
    r.x = ((unsigned)f2bf(a.y) << 16) | f2bf(a.x);
    r.y = ((unsigned)f2bf(a.w) << 16) | f2bf(a.z);
    r.z = ((unsigned)f2bf(b.y) << 16) | f2bf(b.x);
    r.w = ((unsigned)f2bf(b.w) << 16) | f2bf(b.z);
    return r;
}
__device__ __forceinline__ void atomic_pk_bf16(unsigned short* p, unsigned v) {
    asm volatile("global_atomic_pk_add_bf16 %0, %1, off" :: "v"(p), "v"(v) : "memory");
}

// ---------------------------------------------------------------------------
// Weight pre-convert: fp32 [L][K][128] -> bf16 fragment-major [L][K/32][8][64][8]
// value(l,kk,nt,lane,j) = W[l][kk*32 + 8*(lane>>4) + j][nt*16 + (lane&15)]
// ---------------------------------------------------------------------------
__global__ void wconv_kernel(const float* __restrict__ src, unsigned short* __restrict__ dst,
                             int K, int total)
{
    int i = blockIdx.x * 256 + threadIdx.x;
    if (i >= total) return;
    int layer_sz = K * 128;
    int l = i / layer_sz;
    int r = i - l * layer_sz;
    int j    = r & 7;
    int lane = (r >> 3) & 63;
    int nt   = (r >> 9) & 7;
    int kk   = r >> 12;
    int row  = kk * 32 + ((lane >> 4) << 3) + j;
    int col  = nt * 16 + (lane & 15);
    dst[i] = f2bf(src[(size_t)l * layer_sz + row * 128 + col]);
}

__global__ void h2b_kernel(const float* __restrict__ src, unsigned short* __restrict__ dst, int total8)
{
    int i = blockIdx.x * 256 + threadIdx.x;
    if (i >= total8) return;
    float4 a = ((const float4*)src)[2 * i];
    float4 b = ((const float4*)src)[2 * i + 1];
    ((uint4*)dst)[i] = pack8(a, b);
}

__global__ void count_kernel(const int* __restrict__ ht, float* __restrict__ cnt, int m)
{
    int e = blockIdx.x * 256 + threadIdx.x;
    if (e < m) {
        atomicAdd(&cnt[ht[2 * e]],     1.0f);
        atomicAdd(&cnt[ht[2 * e + 1]], 1.0f);
    }
}

// ---------------------------------------------------------------------------
// Barrier-free fused edge kernel. ONE wave per block, 32 edges per wave
// (2 MFMA M-tiles). 15625 blocks cover 500000 edges exactly (no tails).
// A: global gathers (Hb bf16) + private LDS (E/en, XOR-swizzled).
// B: streamed global->reg, reloaded in place after last use (1-step lookahead
//    via compiler vmcnt). No __syncthreads, no inter-wave coupling.
// ---------------------------------------------------------------------------
template <bool E_F32, bool WRITE_E>
__global__ __launch_bounds__(64, 3)
void edge_mfma_kernel(const unsigned short* __restrict__ Hb,
                      const float* __restrict__ E0,
                      const unsigned short* __restrict__ Ebf,
                      unsigned short* __restrict__ Eout,
                      const int* __restrict__ ht,
                      const unsigned short* __restrict__ Weu,
                      const unsigned short* __restrict__ Wf,
                      const unsigned short* __restrict__ Wb,
                      const float* __restrict__ beu,
                      const float* __restrict__ lneg, const float* __restrict__ lneb,
                      const float* __restrict__ bfw, const float* __restrict__ bbw,
                      unsigned short* __restrict__ agg)
{
    __shared__ unsigned char en[8192];      // 32 E/en rows, bf16, XOR-swizzled

    const int ln  = threadIdx.x;
    const int g   = ln >> 4;
    const int c15 = ln & 15;
    const int ew0 = blockIdx.x * 32;

    // ---- stage 32 E rows into LDS (bf16, XOR-swizzled) ----
#pragma unroll
    for (int it = 0; it < 8; ++it) {
        int lin = it * 1024 + ln * 16;      // dest byte in [0,8192)
        int row = lin >> 8;
        int e   = ew0 + row;
        int elem = (lin & 255) >> 1;
        uint4 pk;
        if (E_F32) {
            const float* s = E0 + (size_t)e * D + elem;
            pk = pack8(*(const float4*)s, *(const float4*)(s + 4));
        } else {
            pk = *(const uint4*)(Ebf + (size_t)e * D + elem);
        }
        *(uint4*)(en + (lin ^ ((row & 7) << 4))) = pk;
    }

    // ---- per-lane A-row pointers (lane's rows: c15 and c15+16) ----
    int2 htA0 = ((const int2*)ht)[ew0 + c15];
    int2 htA1 = ((const int2*)ht)[ew0 + 16 + c15];
    const unsigned short* hrow0 = Hb + (size_t)htA0.x * D;
    const unsigned short* hrow1 = Hb + (size_t)htA1.x * D;
    const unsigned short* trow0 = Hb + (size_t)htA0.y * D;
    const unsigned short* trow1 = Hb + (size_t)htA1.y * D;
    const int enoff0 = c15 * 256;
    const int enoff1 = (16 + c15) * 256;
    const int swz    = (c15 & 7) << 4;

    f32x4 acc[2][8];

    // =========================== GEMM1: triple(384) @ Weu ===================
#pragma unroll
    for (int m = 0; m < 2; ++m)
#pragma unroll
        for (int nt = 0; nt < 8; ++nt) acc[m][nt] = (f32x4){0.f, 0.f, 0.f, 0.f};

    {
        const uint4* Wg = (const uint4*)Weu;
        uint4 bc[8];
        bf16x8 a0, a1, a0n, a1n;
        auto loadA = [&](int kk, int m) -> bf16x8 {
            if (kk < 4)
                return *(const bf16x8*)((m ? hrow1 : hrow0) + kk * 32 + g * 8);
            if (kk < 8)
                return *(const bf16x8*)(en + (((m ? enoff1 : enoff0) + (kk - 4) * 64 + g * 16) ^ swz));
            return *(const bf16x8*)((m ? trow1 : trow0) + (kk - 8) * 32 + g * 8);
        };
#pragma unroll
        for (int nt = 0; nt < 8; ++nt) bc[nt] = Wg[nt * 64 + ln];
        a0 = loadA(0, 0); a1 = loadA(0, 1);
#pragma unroll
        for (int kk = 0; kk < 12; ++kk) {
            if (kk < 11) { a0n = loadA(kk + 1, 0); a1n = loadA(kk + 1, 1); }
#pragma unroll
            for (int nt = 0; nt < 8; ++nt) {
                bf16x8 b = *(const bf16x8*)&bc[nt];
                acc[0][nt] = __builtin_amdgcn_mfma_f32_16x16x32_bf16(a0, b, acc[0][nt], 0, 0, 0);
                acc[1][nt] = __builtin_amdgcn_mfma_f32_16x16x32_bf16(a1, b, acc[1][nt], 0, 0, 0);
                if (kk < 11) bc[nt] = Wg[(kk + 1) * 512 + nt * 64 + ln];   // reload in place
            }
            a0 = a0n; a1 = a1n;
        }
    }

    // ============ bias + leaky + residual + LayerNorm -> en (LDS) ===========
    {
        float be[8], lg[8], lb[8];
#pragma unroll
        for (int nt = 0; nt < 8; ++nt) {
            be[nt] = beu[nt * 16 + c15];
            lg[nt] = lneg[nt * 16 + c15];
            lb[nt] = lneb[nt * 16 + c15];
        }
#pragma unroll
        for (int m = 0; m < 2; ++m) {
            float s[4] = {0.f,0.f,0.f,0.f}, ss[4] = {0.f,0.f,0.f,0.f};
#pragma unroll
            for (int nt = 0; nt < 8; ++nt) {
#pragma unroll
                for (int r = 0; r < 4; ++r) {
                    int row = m * 16 + g * 4 + r;
                    float x = acc[m][nt][r] + be[nt];
                    x = (x >= 0.f) ? x : SLOPE * x;
                    int lin = row * 256 + (nt * 16 + c15) * 2;
                    x += bf2f(*(const unsigned short*)(en + (lin ^ ((row & 7) << 4))));
                    acc[m][nt][r] = x;
                    s[r] += x; ss[r] += x * x;
                }
            }
#pragma unroll
            for (int d = 1; d < 16; d <<= 1) {
#pragma unroll
                for (int r = 0; r < 4; ++r) {
                    s[r]  += __shfl_xor(s[r],  d);
                    ss[r] += __shfl_xor(ss[r], d);
                }
            }
            float mu[4], rs[4];
#pragma unroll
            for (int r = 0; r < 4; ++r) {
                mu[r] = s[r] * (1.0f / 128.0f);
                float var = ss[r] * (1.0f / 128.0f) - mu[r] * mu[r];
                rs[r] = rsqrtf(var + EPS);
            }
#pragma unroll
            for (int nt = 0; nt < 8; ++nt) {
#pragma unroll
                for (int r = 0; r < 4; ++r) {
                    int row = m * 16 + g * 4 + r;
                    float xn = (acc[m][nt][r] - mu[r]) * rs[r] * lg[nt] + lb[nt];
                    int lin = row * 256 + (nt * 16 + c15) * 2;
                    *(unsigned short*)(en + (lin ^ ((row & 7) << 4))) = f2bf(xn);
                }
            }
        }
    }

    // ---- write E_new to global (layer 0 only) ----
    if (WRITE_E) {
#pragma unroll
        for (int it = 0; it < 8; ++it) {
            int lin = it * 1024 + ln * 16;
            int row = lin >> 8;
            *(uint4*)(Eout + (size_t)(ew0 + row) * D + ((lin & 255) >> 1)) =
                *(const uint4*)(en + (lin ^ ((row & 7) << 4)));
        }
    }

    // =================== GEMM2 ([head|en] @ Wf) + GEMM3 ([tail|en] @ Wb) ====
#pragma unroll
    for (int pass = 0; pass < 2; ++pass) {
        const uint4* Wg = (const uint4*)(pass == 0 ? Wf : Wb);
        const unsigned short* r0 = pass == 0 ? hrow0 : trow0;
        const unsigned short* r1 = pass == 0 ? hrow1 : trow1;
#pragma unroll
        for (int m = 0; m < 2; ++m)
#pragma unroll
            for (int nt = 0; nt < 8; ++nt) acc[m][nt] = (f32x4){0.f, 0.f, 0.f, 0.f};

        {
            uint4 bc[8];
            bf16x8 a0, a1, a0n, a1n;
            auto loadA = [&](int kk, int m) -> bf16x8 {
                if (kk < 4)
                    return *(const bf16x8*)((m ? r1 : r0) + kk * 32 + g * 8);
                return *(const bf16x8*)(en + (((m ? enoff1 : enoff0) + (kk - 4) * 64 + g * 16) ^ swz));
            };
#pragma unroll
            for (int nt = 0; nt < 8; ++nt) bc[nt] = Wg[nt * 64 + ln];
            a0 = loadA(0, 0); a1 = loadA(0, 1);
#pragma unroll
            for (int kk = 0; kk < 8; ++kk) {
                if (kk < 7) { a0n = loadA(kk + 1, 0); a1n = loadA(kk + 1, 1); }
#pragma unroll
                for (int nt = 0; nt < 8; ++nt) {
                    bf16x8 b = *(const bf16x8*)&bc[nt];
                    acc[0][nt] = __builtin_amdgcn_mfma_f32_16x16x32_bf16(a0, b, acc[0][nt], 0, 0, 0);
                    acc[1][nt] = __builtin_amdgcn_mfma_f32_16x16x32_bf16(a1, b, acc[1][nt], 0, 0, 0);
                    if (kk < 7) bc[nt] = Wg[(kk + 1) * 512 + nt * 64 + ln];
                }
                a0 = a0n; a1 = a1n;
            }
        }

        // ---- scatter: packed bf16x2 atomics (even lanes nt0-3, odd nt4-7) --
        {
            const float* bias = pass == 0 ? bfw : bbw;
            float bv[8];
#pragma unroll
            for (int nt = 0; nt < 8; ++nt) bv[nt] = bias[nt * 16 + c15];
#pragma unroll
            for (int m = 0; m < 2; ++m) {
#pragma unroll
                for (int r = 0; r < 4; ++r) {
                    int e = ew0 + m * 16 + g * 4 + r;
                    int2 p = ((const int2*)ht)[e];
                    int dst = pass == 0 ? p.y : p.x;       // fwd->tail, back->head
                    unsigned short* base = agg + (size_t)dst * D + (c15 & ~1);
#pragma unroll
                    for (int nt = 0; nt < 8; ++nt) {
                        float v = acc[m][nt][r] + bv[nt];
                        float o = __shfl_xor(v, 1);
                        float lo = (ln & 1) ? o : v;
                        float hi = (ln & 1) ? v : o;
                        unsigned pk = ((unsigned)f2bf(hi) << 16) | f2bf(lo);
                        if ((ln & 1) == (nt >> 2))
                            atomic_pk_bf16(base + nt * 16, pk);
                    }
                }
            }
        }
    }
}

// ---------------------------------------------------------------------------
// node_kernel: H = LN(leaky(agg/max(cnt,1)) + H); writes f32 Hout + bf16 Hb.
// ---------------------------------------------------------------------------
__global__ __launch_bounds__(256)
void node_kernel(const float* __restrict__ Hin, const unsigned short* __restrict__ aggb,
                 const float* __restrict__ cnt, const float* __restrict__ g,
                 const float* __restrict__ b, float* __restrict__ Hout,
                 unsigned short* __restrict__ Hb, int n)
{
    const int wave = threadIdx.x >> 6, lane = threadIdx.x & 63;
    const int node = blockIdx.x * 4 + wave;
    if (node >= n) return;

    float inv = 1.0f / fmaxf(cnt[node], 1.0f);
    size_t base = (size_t)node * D;

    float a0 = bf2f(aggb[base + lane]) * inv;
    float a1 = bf2f(aggb[base + lane + 64]) * inv;
    a0 = (a0 >= 0.0f) ? a0 : SLOPE * a0;
    a1 = (a1 >= 0.0f) ? a1 : SLOPE * a1;
    float x0 = a0 + Hin[base + lane];
    float x1 = a1 + Hin[base + lane + 64];

    float s = x0 + x1, ss = x0 * x0 + x1 * x1;
#pragma unroll
    for (int d = 1; d < 64; d <<= 1) {
        s  += __shfl_xor(s, d);
        ss += __shfl_xor(ss, d);
    }
    float mu  = s * (1.0f / 128.0f);
    float var = ss * (1.0f / 128.0f) - mu * mu;
    float rs  = rsqrtf(var + EPS);

    float o0 = (x0 - mu) * rs * g[lane]      + b[lane];
    float o1 = (x1 - mu) * rs * g[lane + 64] + b[lane + 64];
    Hout[base + lane]      = o0;
    Hout[base + lane + 64] = o1;
    Hb[base + lane]        = f2bf(o0);
    Hb[base + lane + 64]   = f2bf(o1);
}

// ---------------------------------------------------------------------------
extern "C" void kernel_launch(void* const* d_in, const int* in_sizes, int n_in,
                              void* d_out, int out_size, void* d_ws, size_t ws_size,
                              hipStream_t stream)
{
    const float* H0   = (const float*)d_in[0];
    const float* E0   = (const float*)d_in[1];
    const int*   ht   = (const int*)d_in[2];
    const float* Weu  = (const float*)d_in[4];
    const float* beu  = (const float*)d_in[5];
    const float* lneg = (const float*)d_in[6];
    const float* lneb = (const float*)d_in[7];
    const float* Wf   = (const float*)d_in[8];
    const float* bfw  = (const float*)d_in[9];
    const float* Wb   = (const float*)d_in[10];
    const float* bbw  = (const float*)d_in[11];
    const float* lnhg = (const float*)d_in[12];
    const float* lnhb = (const float*)d_in[13];

    float* Hout = (float*)d_out;

    // workspace layout
    char* ws = (char*)d_ws;
    unsigned short* aggb   = (unsigned short*)ws;                   //  25,600,000
    float*          cnt    = (float*)(ws + 25600000);               //     400,000
    unsigned short* Ebuf   = (unsigned short*)(ws + 26000000);      // 128,000,000
    unsigned short* Hb     = (unsigned short*)(ws + 154000000);     //  25,600,000
    unsigned short* Weu_sw = (unsigned short*)(ws + 179600000);     //     196,608
    unsigned short* Wf_sw  = (unsigned short*)(ws + 179796608);     //     131,072
    unsigned short* Wb_sw  = (unsigned short*)(ws + 179927680);     //     131,072

    wconv_kernel<<<(2*384*128 + 255)/256, 256, 0, stream>>>(Weu, Weu_sw, 384, 2*384*128);
    wconv_kernel<<<(2*256*128 + 255)/256, 256, 0, stream>>>(Wf,  Wf_sw,  256, 2*256*128);
    wconv_kernel<<<(2*256*128 + 255)/256, 256, 0, stream>>>(Wb,  Wb_sw,  256, 2*256*128);
    h2b_kernel<<<(N_NODES * D / 8 + 255)/256, 256, 0, stream>>>(H0, Hb, N_NODES * D / 8);

    hipMemsetAsync(cnt, 0, (size_t)N_NODES * sizeof(float), stream);
    count_kernel<<<(M_EDGES + 255) / 256, 256, 0, stream>>>(ht, cnt, M_EDGES);

    const int eblocks = M_EDGES / 32;   // 15625, exact

    for (int l = 0; l < 2; ++l) {
        const float* Hin = (l == 0) ? H0 : Hout;
        hipMemsetAsync(aggb, 0, (size_t)N_NODES * D * sizeof(unsigned short), stream);

        if (l == 0) {
            edge_mfma_kernel<true, true><<<eblocks, 64, 0, stream>>>(
                Hb, E0, nullptr, Ebuf, ht,
                Weu_sw, Wf_sw, Wb_sw,
                beu, lneg, lneb, bfw, bbw, aggb);
        } else {
            edge_mfma_kernel<false, false><<<eblocks, 64, 0, stream>>>(
                Hb, nullptr, Ebuf, nullptr, ht,
                Weu_sw + 49152, Wf_sw + 32768, Wb_sw + 32768,
                beu + D, lneg + D, lneb + D, bfw + D, bbw + D, aggb);
        }

        node_kernel<<<(N_NODES + 3) / 4, 256, 0, stream>>>(
            Hin, aggb, cnt, lnhg + (size_t)l * D, lnhb + (size_t)l * D, Hout, Hb, N_NODES);
    }
}